// Round 5
// baseline (824.194 us; speedup 1.0000x reference)
//
#include <hip/hip_runtime.h>
#include <hip/hip_bf16.h>
#include <stdint.h>

#define H 180
#define W 180
#define HW 32400
#define CIN 256
#define NCLS 10
#define NPROP 200
#define WTAP 589824    // 9 taps * 16 cig16 * 256 co * 2 half * 8 = per split variant
#define WTAP2 36864    // conv2: 9 taps * 32 cig * 16 co * 8 (co zero-padded 10->16)

// ---- workspace layout ----
// Phase 1 (conv1 -> conv2): x buffer owns [0, 132,710,400).
// Phase 2 (post-conv2): x dead; small buffers alias into it. ws need = 132.7 MB.
#define OFF_X      0ULL
#define OFF_NMS    0ULL
#define OFF_HIST   5184000ULL
#define OFF_CNT    5249536ULL
#define OFF_CAND   5249568ULL
#define OFF_BSEL   5380640ULL
#define OFF_TPOS   5380672ULL
#define OFF_TLAB   5383872ULL

typedef __attribute__((ext_vector_type(8))) short short8;
typedef __attribute__((ext_vector_type(4))) float f32x4;
typedef __attribute__((ext_vector_type(16))) float f32x16;

__device__ __forceinline__ float sigm(float v) { return 1.0f / (1.0f + expf(-v)); }

__device__ __forceinline__ unsigned bfround(unsigned u) {
    return (u + 0x7FFFu + ((u >> 16) & 1u)) >> 16;
}
__device__ __forceinline__ void splitbf(float v, short &hi, short &lo) {
    unsigned u = __float_as_uint(v);
    unsigned hb = bfround(u);
    float fh = __uint_as_float(hb << 16);
    unsigned lb = bfround(__float_as_uint(v - fh));
    hi = (short)hb; lo = (short)lb;
}

// conv1 weights: OIHW f32 -> [tap][g(ci16)][co][half][8] bf16 hi|lo  (32x32x16 A-frag order)
__global__ void split_w_kernel(const float* __restrict__ w1, short* __restrict__ Wq)
{
    int idx = blockIdx.x * 256 + threadIdx.x;
    if (idx >= WTAP) return;
    int e = idx & 7, h = (idx >> 3) & 1, co = (idx >> 4) & 255, g = (idx >> 12) & 15, tap = idx >> 16;
    int ci = g * 16 + h * 8 + e;
    float v = w1[((size_t)co * CIN + ci) * 9 + tap];
    short hh, ll; splitbf(v, hh, ll);
    Wq[idx] = hh; Wq[WTAP + idx] = ll;
}

// conv2 weights: [10][256][9] f32 -> [tap][cig][co16][8] bf16 hi|lo (16x16x32 A-frag order)
__global__ void split_w2_kernel(const float* __restrict__ w2, short* __restrict__ Wq2)
{
    int idx = blockIdx.x * 256 + threadIdx.x;
    if (idx >= WTAP2) return;
    int e = idx & 7, co = (idx >> 3) & 15, cig = (idx >> 7) & 31, tap = idx >> 12;
    int ci = cig * 8 + e;
    float v = (co < NCLS) ? w2[((size_t)co * CIN + ci) * 9 + tap] : 0.f;
    short h, l; splitbf(v, h, l);
    Wq2[idx] = h; Wq2[WTAP2 + idx] = l;
}

// ---------------- conv1 (3x3, 256->256) + BN + ReLU via MFMA 32x32x16 bf16x3 ----------
// grid (6, 45, 8 = b*2 + cogroup), block 256 (4 waves)
// block out: 128 co x (4 rows x 32 cols); wave: 32 co x 4r x 32c (acc 4 x f32x16)
__global__ __launch_bounds__(256, 3)
void conv1_mfma(const float* __restrict__ in, const short* __restrict__ Wq,
                const float* __restrict__ gamma, const float* __restrict__ beta,
                const float* __restrict__ mean, const float* __restrict__ var,
                float* __restrict__ xout)
{
    __shared__ short Xs[2][6][34][36];   // [hi|lo][row][col][ci pad36] = 29,376 B
    const int b    = blockIdx.z >> 1;
    const int co0  = (blockIdx.z & 1) * 128;
    const int y0   = blockIdx.y * 4;
    const int col0 = blockIdx.x * 32;
    const int tid  = threadIdx.x;
    const int w    = tid >> 6;
    const int lane = tid & 63;
    const int lc = lane & 31, hf = lane >> 5;
    const int cobase = co0 + w * 32;

    f32x16 acc[4];
    #pragma unroll
    for (int r = 0; r < 4; ++r)
        #pragma unroll
        for (int q = 0; q < 16; ++q) acc[r][q] = 0.f;

    // staging decode: 816 items = 4 ci8-slices x 6 rows x 34 cols
    int sl_[4], rr_[4], cc_[4];
    bool va_[4], inb_[4];
    const float* src_[4];
    #pragma unroll
    for (int it = 0; it < 4; ++it) {
        int is = tid + it * 256;
        bool va = is < 816;
        int isc = va ? is : 0;
        int sl = isc / 204, rem = isc % 204;
        int r = rem / 34, c = rem % 34;
        int gy = y0 - 1 + r, gx = col0 - 1 + c;
        bool inb = va && ((unsigned)gy < (unsigned)H) && ((unsigned)gx < (unsigned)W);
        sl_[it]=sl; rr_[it]=r; cc_[it]=c; va_[it]=va; inb_[it]=inb;
        src_[it] = in + ((size_t)(b*CIN + sl*8) * H + gy) * W + gx;
    }

    float sA[4][8];
    // prologue: stage chunk 0
    #pragma unroll
    for (int it = 0; it < 4; ++it)
        #pragma unroll
        for (int e = 0; e < 8; ++e)
            sA[it][e] = inb_[it] ? src_[it][(size_t)e * HW] : 0.f;
    #pragma unroll
    for (int it = 0; it < 4; ++it) {
        if (va_[it]) {
            short h8[8], l8[8];
            #pragma unroll
            for (int e = 0; e < 8; ++e) splitbf(sA[it][e], h8[e], l8[e]);
            short8 vh, vl;
            #pragma unroll
            for (int e = 0; e < 8; ++e) { vh[e] = h8[e]; vl[e] = l8[e]; }
            *(short8*)&Xs[0][rr_[it]][cc_[it]][sl_[it]*8] = vh;
            *(short8*)&Xs[1][rr_[it]][cc_[it]][sl_[it]*8] = vl;
        }
    }
    __syncthreads();

#define TRI(R, AH, AL, BH, BL) { f32x16 a_ = acc[R]; \
    a_ = __builtin_amdgcn_mfma_f32_32x32x16_bf16(AH, BH, a_, 0, 0, 0); \
    a_ = __builtin_amdgcn_mfma_f32_32x32x16_bf16(AH, BL, a_, 0, 0, 0); \
    a_ = __builtin_amdgcn_mfma_f32_32x32x16_bf16(AL, BH, a_, 0, 0, 0); \
    acc[R] = a_; }

    for (int kc = 0; kc < 8; ++kc) {
        const bool more = (kc < 7);
        // T14: issue next chunk's global loads before compute
        if (more) {
            const size_t coff = (size_t)(kc + 1) * 32 * HW;
            #pragma unroll
            for (int it = 0; it < 4; ++it)
                #pragma unroll
                for (int e = 0; e < 8; ++e)
                    sA[it][e] = inb_[it] ? src_[it][coff + (size_t)e * HW] : 0.f;
        }
        #pragma unroll
        for (int s = 0; s < 2; ++s) {
            const int g = kc * 2 + s;
            const int ko = s * 16 + hf * 8;
            #pragma unroll
            for (int dx = 0; dx < 3; ++dx) {
                short8 ah[3], al[3];
                #pragma unroll
                for (int dy = 0; dy < 3; ++dy) {
                    const size_t off = (((size_t)(dy*3 + dx)*16 + g)*256 + cobase + lc)*16 + hf*8;
                    ah[dy] = *(const short8*)(Wq + off);
                    al[dy] = *(const short8*)(Wq + WTAP + off);
                }
                const int cc = lc + dx;
                // sliding 3-row B window (rows r..r+2 live)
                short8 w0h = *(const short8*)&Xs[0][0][cc][ko];
                short8 w0l = *(const short8*)&Xs[1][0][cc][ko];
                short8 w1h = *(const short8*)&Xs[0][1][cc][ko];
                short8 w1l = *(const short8*)&Xs[1][1][cc][ko];
                short8 w2h = *(const short8*)&Xs[0][2][cc][ko];
                short8 w2l = *(const short8*)&Xs[1][2][cc][ko];
                TRI(0, ah[0], al[0], w0h, w0l);
                TRI(0, ah[1], al[1], w1h, w1l);
                TRI(0, ah[2], al[2], w2h, w2l);
                w0h = *(const short8*)&Xs[0][3][cc][ko];
                w0l = *(const short8*)&Xs[1][3][cc][ko];
                TRI(1, ah[0], al[0], w1h, w1l);
                TRI(1, ah[1], al[1], w2h, w2l);
                TRI(1, ah[2], al[2], w0h, w0l);
                w1h = *(const short8*)&Xs[0][4][cc][ko];
                w1l = *(const short8*)&Xs[1][4][cc][ko];
                TRI(2, ah[0], al[0], w2h, w2l);
                TRI(2, ah[1], al[1], w0h, w0l);
                TRI(2, ah[2], al[2], w1h, w1l);
                w2h = *(const short8*)&Xs[0][5][cc][ko];
                w2l = *(const short8*)&Xs[1][5][cc][ko];
                TRI(3, ah[0], al[0], w0h, w0l);
                TRI(3, ah[1], al[1], w1h, w1l);
                TRI(3, ah[2], al[2], w2h, w2l);
            }
        }
        __syncthreads();
        if (more) {
            #pragma unroll
            for (int it = 0; it < 4; ++it) {
                if (va_[it]) {
                    short h8[8], l8[8];
                    #pragma unroll
                    for (int e = 0; e < 8; ++e) splitbf(sA[it][e], h8[e], l8[e]);
                    short8 vh, vl;
                    #pragma unroll
                    for (int e = 0; e < 8; ++e) { vh[e] = h8[e]; vl[e] = l8[e]; }
                    *(short8*)&Xs[0][rr_[it]][cc_[it]][sl_[it]*8] = vh;
                    *(short8*)&Xs[1][rr_[it]][cc_[it]][sl_[it]*8] = vl;
                }
            }
        }
        __syncthreads();
    }
#undef TRI

    // epilogue: BN + ReLU + store. C: col=lane&31, co_off=(reg&3)+8*(reg>>2)+4*hf
    float scv[16], shv[16];
    #pragma unroll
    for (int q = 0; q < 16; ++q) {
        int co = cobase + (q & 3) + 8 * (q >> 2) + 4 * hf;
        float s = gamma[co] / sqrtf(var[co] + 1e-5f);
        scv[q] = s; shv[q] = beta[co] - mean[co] * s;
    }
    const int x = col0 + lc;
    if (x < W) {
        #pragma unroll
        for (int r = 0; r < 4; ++r) {
            const int y = y0 + r;
            #pragma unroll
            for (int q = 0; q < 16; ++q) {
                int co = cobase + (q & 3) + 8 * (q >> 2) + 4 * hf;
                float v = fmaxf(fmaf(acc[r][q], scv[q], shv[q]), 0.f);
                xout[((size_t)(b*CIN + co) * H + y) * W + x] = v;
            }
        }
    }
}

// ---------------- conv2 (3x3, 256->10) + bias via MFMA 16x16x32 bf16x3 ----------------
__global__ __launch_bounds__(256, 2)
void conv2_mfma(const float* __restrict__ x, const short* __restrict__ Wq2,
                const float* __restrict__ bias, float* __restrict__ dense)
{
    __shared__ short Xs[2][2][6][34][36];
    const int b    = blockIdx.z;
    const int y0   = blockIdx.y * 4;
    const int col0 = blockIdx.x * 32;
    const int tid  = threadIdx.x;
    const int w    = tid >> 6;
    const int lane = tid & 63;
    const int li = lane & 15, lg = lane >> 4;
    const int c16w = w & 1, rh = w >> 1;

    f32x4 acc2[2];
    acc2[0] = (f32x4){0.f,0.f,0.f,0.f};
    acc2[1] = (f32x4){0.f,0.f,0.f,0.f};

    int sl_[4], rr_[4], cc_[4];
    bool va_[4], inb_[4];
    const float* src_[4];
    #pragma unroll
    for (int it = 0; it < 4; ++it) {
        int is = tid + it * 256;
        bool va = is < 816;
        int isc = va ? is : 0;
        int sl = isc / 204, rem = isc % 204;
        int r = rem / 34, c = rem % 34;
        int gy = y0 - 1 + r, gx = col0 - 1 + c;
        bool inb = va && ((unsigned)gy < (unsigned)H) && ((unsigned)gx < (unsigned)W);
        sl_[it]=sl; rr_[it]=r; cc_[it]=c; va_[it]=va; inb_[it]=inb;
        src_[it] = x + ((size_t)(b*CIN + sl*8) * H + gy) * W + gx;
    }

    float sA[4][8];
    #pragma unroll
    for (int it = 0; it < 4; ++it)
        #pragma unroll
        for (int e = 0; e < 8; ++e)
            sA[it][e] = inb_[it] ? src_[it][(size_t)e * HW] : 0.f;
    #pragma unroll
    for (int it = 0; it < 4; ++it) {
        if (va_[it]) {
            short h[8], l[8];
            #pragma unroll
            for (int e = 0; e < 8; ++e) splitbf(sA[it][e], h[e], l[e]);
            short8 vh, vl;
            #pragma unroll
            for (int e = 0; e < 8; ++e) { vh[e] = h[e]; vl[e] = l[e]; }
            *(short8*)&Xs[0][0][rr_[it]][cc_[it]][sl_[it]*8] = vh;
            *(short8*)&Xs[0][1][rr_[it]][cc_[it]][sl_[it]*8] = vl;
        }
    }
    __syncthreads();

    for (int kc = 0; kc < 8; ++kc) {
        const int cur = kc & 1, nxt = cur ^ 1;
        const bool more = (kc < 7);
        if (more) {
            const size_t coff = (size_t)(kc + 1) * 32 * HW;
            #pragma unroll
            for (int it = 0; it < 4; ++it)
                #pragma unroll
                for (int e = 0; e < 8; ++e)
                    sA[it][e] = inb_[it] ? src_[it][coff + (size_t)e * HW] : 0.f;
        }
        const int cig = kc * 4 + lg;
        const short* pA = Wq2 + ((size_t)cig * 16 + li) * 8;
        #pragma unroll
        for (int dx = 0; dx < 3; ++dx) {
            short8 a_h[3], a_l[3];
            #pragma unroll
            for (int dy = 0; dy < 3; ++dy) {
                const int off = (dy*3 + dx) * 4096;
                a_h[dy] = *(const short8*)(pA + off);
                a_l[dy] = *(const short8*)(pA + WTAP2 + off);
            }
            const int ccol = c16w * 16 + li + dx;
            short8 bh[4], bl[4];
            #pragma unroll
            for (int rr = 0; rr < 4; ++rr) {
                bh[rr] = *(const short8*)&Xs[cur][0][rh*2 + rr][ccol][lg*8];
                bl[rr] = *(const short8*)&Xs[cur][1][rh*2 + rr][ccol][lg*8];
            }
            #pragma unroll
            for (int dy = 0; dy < 3; ++dy) {
                #pragma unroll
                for (int r2 = 0; r2 < 2; ++r2) {
                    f32x4 a = acc2[r2];
                    a = __builtin_amdgcn_mfma_f32_16x16x32_bf16(a_h[dy], bh[r2+dy], a, 0, 0, 0);
                    a = __builtin_amdgcn_mfma_f32_16x16x32_bf16(a_h[dy], bl[r2+dy], a, 0, 0, 0);
                    a = __builtin_amdgcn_mfma_f32_16x16x32_bf16(a_l[dy], bh[r2+dy], a, 0, 0, 0);
                    acc2[r2] = a;
                }
            }
        }
        if (more) {
            #pragma unroll
            for (int it = 0; it < 4; ++it) {
                if (va_[it]) {
                    short h[8], l[8];
                    #pragma unroll
                    for (int e = 0; e < 8; ++e) splitbf(sA[it][e], h[e], l[e]);
                    short8 vh, vl;
                    #pragma unroll
                    for (int e = 0; e < 8; ++e) { vh[e] = h[e]; vl[e] = l[e]; }
                    *(short8*)&Xs[nxt][0][rr_[it]][cc_[it]][sl_[it]*8] = vh;
                    *(short8*)&Xs[nxt][1][rr_[it]][cc_[it]][sl_[it]*8] = vl;
                }
            }
        }
        __syncthreads();
    }

    #pragma unroll
    for (int r2 = 0; r2 < 2; ++r2) {
        const int y = y0 + rh*2 + r2;
        const int xc = col0 + c16w*16 + li;
        if (xc < W) {
            #pragma unroll
            for (int q = 0; q < 4; ++q) {
                int co = lg*4 + q;
                if (co < NCLS)
                    dense[((size_t)(b*NCLS + co) * H + y) * W + xc] = acc2[r2][q] + bias[co];
            }
        }
    }
}

// ---------------- sigmoid + 3x3 NMS ----------------
__global__ void nms_kernel(const float* __restrict__ dense, float* __restrict__ nms)
{
    const int x = threadIdx.x;
    if (x >= W) return;
    const int bk = blockIdx.x;
    const int y = blockIdx.y;
    const int k = bk % NCLS;
    const float* p = dense + (size_t)bk * HW;
    float c = sigm(p[y*W + x]);
    float outv;
    if (k >= 8) {
        outv = c;
    } else if (x == 0 || x == W-1 || y == 0 || y == H-1) {
        outv = 0.f;
    } else {
        float m = c;
        #pragma unroll
        for (int dy = -1; dy <= 1; ++dy)
            #pragma unroll
            for (int dx = -1; dx <= 1; ++dx) {
                if (dy == 0 && dx == 0) continue;
                m = fmaxf(m, sigm(p[(y+dy)*W + (x+dx)]));
            }
        outv = (c == m) ? c : 0.f;
    }
    nms[(size_t)bk * HW + y*W + x] = outv;
}

// ---------------- histogram / scan / collect / sort / gather ----------------
__global__ void hist_kernel(const float* __restrict__ nms, int* __restrict__ hist)
{
    __shared__ int h[4096];
    const int b = blockIdx.y;
    for (int l = threadIdx.x; l < 4096; l += 256) h[l] = 0;
    __syncthreads();
    const float* p = nms + (size_t)b * (NCLS*HW);
    for (int i = blockIdx.x*256 + threadIdx.x; i < NCLS*HW; i += gridDim.x*256) {
        float v = p[i];
        if (v > 0.f) {
            int bin = (int)(v * 4096.f);
            if (bin > 4095) bin = 4095;
            atomicAdd(&h[bin], 1);
        }
    }
    __syncthreads();
    for (int l = threadIdx.x; l < 4096; l += 256)
        if (h[l]) atomicAdd(&hist[b*4096 + l], h[l]);
}

__global__ void scan_kernel(const int* __restrict__ hist, int* __restrict__ bsel)
{
    __shared__ int ss[256];
    const int b = blockIdx.x;
    const int t = threadIdx.x;
    const int base = 4096 - 16*(t+1);
    int s = 0;
    #pragma unroll
    for (int i = 0; i < 16; ++i) s += hist[b*4096 + base + i];
    ss[t] = s;
    __syncthreads();
    for (int off = 1; off < 256; off <<= 1) {
        int v = (t >= off) ? ss[t-off] : 0;
        __syncthreads();
        ss[t] += v;
        __syncthreads();
    }
    int incl = ss[t];
    int excl = incl - s;
    if (excl < NPROP && incl >= NPROP) {
        int acc2 = excl, bfound = base;
        for (int bin = base + 15; bin >= base; --bin) {
            acc2 += hist[b*4096 + bin];
            if (acc2 >= NPROP) { bfound = bin; break; }
        }
        bsel[b] = bfound;
    }
    if (t == 255 && ss[255] < NPROP) bsel[b] = 0;
}

__global__ void collect_kernel(const float* __restrict__ nms, const int* __restrict__ bsel,
                               int* __restrict__ cnt, unsigned long long* __restrict__ cand)
{
    const int b = blockIdx.y;
    const int B0 = bsel[b];
    const float* p = nms + (size_t)b * (NCLS*HW);
    for (int i = blockIdx.x*256 + threadIdx.x; i < NCLS*HW; i += gridDim.x*256) {
        float v = p[i];
        if (v > 0.f) {
            int bin = (int)(v * 4096.f);
            if (bin > 4095) bin = 4095;
            if (bin >= B0) {
                int slot = atomicAdd(&cnt[b], 1);
                if (slot < 2048) {
                    unsigned int vb = __float_as_uint(v);
                    cand[(size_t)b*2048 + slot] =
                        ((unsigned long long)(~vb) << 32) | (unsigned int)i;
                }
            }
        }
    }
}

// bitonic sort 2048 (cands ~200-400) + emit
__global__ void sort_emit(const unsigned long long* __restrict__ cand, const int* __restrict__ cnt,
                          const float* __restrict__ nms, const float* __restrict__ bev_pos,
                          float* __restrict__ out, int* __restrict__ tpos, int* __restrict__ tlab)
{
    __shared__ unsigned long long key[2048];
    const int b = blockIdx.x;
    const int t = threadIdx.x;
    int n = cnt[b]; if (n > 2048) n = 2048;
    for (int l = t; l < 2048; l += 1024)
        key[l] = (l < n) ? cand[(size_t)b*2048 + l] : ~0ULL;
    __syncthreads();
    for (int k = 2; k <= 2048; k <<= 1) {
        for (int jj = k >> 1; jj > 0; jj >>= 1) {
            int i  = 2*t - (t & (jj-1));
            int ix = i + jj;
            bool up = ((i & k) == 0);
            unsigned long long a = key[i], c = key[ix];
            if ((a > c) == up) { key[i] = c; key[ix] = a; }
            __syncthreads();
        }
    }
    for (int p = t; p < NPROP; p += 1024) {
        unsigned long long kk = key[p];
        unsigned int idx = (unsigned int)kk;
        if (idx >= (unsigned)(NCLS*HW)) idx = 0;
        int label = idx / HW;
        int pos   = idx % HW;
        out[206400 + b*NPROP + p] = (float)label;
        out[204800 + (b*NPROP + p)*2 + 0] = bev_pos[pos*2 + 0];
        out[204800 + (b*NPROP + p)*2 + 1] = bev_pos[pos*2 + 1];
        tpos[b*NPROP + p] = pos;
        tlab[b*NPROP + p] = label;
        #pragma unroll
        for (int k2 = 0; k2 < NCLS; ++k2)
            out[207200 + (b*NCLS + k2)*NPROP + p] = nms[((size_t)b*NCLS + k2)*HW + pos];
    }
}

__global__ void feat_kernel(const float* __restrict__ bev, const float* __restrict__ cew,
                            const float* __restrict__ ceb, const int* __restrict__ tpos,
                            const int* __restrict__ tlab, float* __restrict__ out)
{
    const int c = blockIdx.x, b = blockIdx.y;
    const int t = threadIdx.x;
    if (t >= NPROP) return;
    int pos = tpos[b*NPROP + t];
    int lab = tlab[b*NPROP + t];
    float v = bev[((size_t)b*CIN + c)*HW + pos] + cew[c*NCLS + lab] + ceb[c];
    out[((size_t)b*CIN + c)*NPROP + t] = v;
}

extern "C" void kernel_launch(void* const* d_in, const int* in_sizes, int n_in,
                              void* d_out, int out_size, void* d_ws, size_t ws_size,
                              hipStream_t stream)
{
    const float* bev   = (const float*)d_in[0];
    const float* bpos  = (const float*)d_in[1];
    const float* w1    = (const float*)d_in[2];
    const float* gamma = (const float*)d_in[3];
    const float* beta  = (const float*)d_in[4];
    const float* mean  = (const float*)d_in[5];
    const float* var   = (const float*)d_in[6];
    const float* w2    = (const float*)d_in[7];
    const float* b2    = (const float*)d_in[8];
    const float* cew   = (const float*)d_in[9];
    const float* ceb   = (const float*)d_in[10];
    float* out = (float*)d_out;
    char* ws = (char*)d_ws;

    float* xbuf = (float*)(ws + OFF_X);
    float* nmsb = (float*)(ws + OFF_NMS);
    int* hist   = (int*)(ws + OFF_HIST);
    int* cnt    = (int*)(ws + OFF_CNT);
    unsigned long long* cand = (unsigned long long*)(ws + OFF_CAND);
    int* bsel   = (int*)(ws + OFF_BSEL);
    int* tpos   = (int*)(ws + OFF_TPOS);
    int* tlab   = (int*)(ws + OFF_TLAB);
    float* dense = out + 215200;
    short* Wq  = (short*)(out + 215200);  // aliases dense until conv2 writes it
    short* Wq2 = (short*)out;             // aliases query_feat region

    split_w_kernel <<<(WTAP  + 255)/256, 256, 0, stream>>>(w1, Wq);
    split_w2_kernel<<<(WTAP2 + 255)/256, 256, 0, stream>>>(w2, Wq2);
    conv1_mfma<<<dim3(6, 45, 8), 256, 0, stream>>>(bev, Wq, gamma, beta, mean, var, xbuf);
    conv2_mfma<<<dim3(6, 45, 4), 256, 0, stream>>>(xbuf, Wq2, b2, dense);
    hipMemsetAsync(ws + OFF_HIST, 0, 65536 + 32, stream);
    nms_kernel  <<<dim3(40, 180),   192, 0, stream>>>(dense, nmsb);
    hist_kernel <<<dim3(32, 4),     256, 0, stream>>>(nmsb, hist);
    scan_kernel <<<4,               256, 0, stream>>>(hist, bsel);
    collect_kernel<<<dim3(64, 4),   256, 0, stream>>>(nmsb, bsel, cnt, cand);
    sort_emit   <<<4,              1024, 0, stream>>>(cand, cnt, nmsb, bpos, out, tpos, tlab);
    feat_kernel <<<dim3(256, 4),    256, 0, stream>>>(bev, cew, ceb, tpos, tlab, out);
}